// Round 16
// baseline (45.441 us; speedup 1.0000x reference)
//
#include <hip/hip_runtime.h>
#include <hip/hip_bf16.h>
#include <math.h>

#define SIDE 48
#define PPOS (SIDE*SIDE)
#define NBATCH 2
#define NHYP 4
#define FD 32
#define RD 8
#define NJ 104
#define NBP (NBATCH*PPOS)       // 4608
#define NOUT (NBP*NHYP)         // 18432
#define THREADS 512
#define NROWS 864               // 6 positions x 144 rows
#define NBLK 768                // one-round grid: 3 blocks/CU x 256 CU
// d_ws dword offsets
#define WS_SR   16              // 9 f32
#define WS_SQR  28              // 9 f32
#define WS_SC   40              // 3 f32
#define WS_RC   64              // 9*128 f32
#define WS_S    1216            // 128 f32
#define WS_T    1344            // 128 f32 (pre-scaled: (T+b1)*32 + 512.5)
#define WS_W2   1472            // 128 f32
#define WS_WBF  1600            // 2048 dw
#define WS_WAF  3648            // 2048 dw
#define WS_PART 5696            // 3*NBLK f32

typedef __attribute__((ext_vector_type(8))) short short8;
typedef __attribute__((ext_vector_type(4))) float f32x4;
typedef __attribute__((ext_vector_type(2))) float f32x2;
union U8 { uint4 u4; short8 s8; };

__device__ __forceinline__ float bflo(unsigned u) { return __uint_as_float(u << 16); }
__device__ __forceinline__ float bfhi(unsigned u) { return __uint_as_float(u & 0xffff0000u); }
__device__ __forceinline__ unsigned packbf2(float a, float b) {
    unsigned ua = __float_as_uint(a), ub = __float_as_uint(b);
    unsigned ra = (ua + 0x7fffu + ((ua >> 16) & 1u)) >> 16;
    unsigned rb = (ub + 0x7fffu + ((ub >> 16) & 1u)) & 0xffff0000u;
    return ra | rb;
}
__device__ __forceinline__ float softplusf(float v) {
    return fmaxf(v, 0.f) + log1pf(expf(-fabsf(v)));
}

#define W1X(kk, j) ((j) < 64 ? sup_w1[(kk)*64 + (j)] : con_w1[(kk)*64 + (j) - 64])

// ---------------- pre-kernel: fold weights once (11 blocks) ----------------
__global__ __launch_bounds__(512) void eml_fold(
    const float* __restrict__ rel, const float* __restrict__ ln_w, const float* __restrict__ ln_b,
    const float* __restrict__ sup_w1, const float* __restrict__ sup_b1,
    const float* __restrict__ sup_w2, const float* __restrict__ sup_b2,
    const float* __restrict__ con_w1, const float* __restrict__ con_b1,
    const float* __restrict__ con_w2, const float* __restrict__ con_b2,
    const float* __restrict__ eml_bias, float* __restrict__ ws)
{
    const int tid = threadIdx.x;
    const int bid = blockIdx.x;
    unsigned* wsd = reinterpret_cast<unsigned*>(ws);
    __shared__ float pS[4][128], pT[4][128];

    if (bid < 8) {
        // B-fragments: lane l holds W^T[col][k] pairs, k0=(l>>4)*8+2j
        int u = bid*512 + tid;
        int sel = u >> 11, v2 = u & 2047;
        int n = v2 >> 8, l = (v2 >> 2) & 63, j = v2 & 3;
        int k0 = (l >> 4)*8 + 2*j, col = n*16 + (l & 15);
        float lo, hi;
        if (sel == 0) {   // Wb (src)
            lo = ln_w[32+k0]*W1X(32+k0,col)     - ln_w[64+k0]*W1X(64+k0,col);
            hi = ln_w[32+k0+1]*W1X(32+k0+1,col) - ln_w[64+k0+1]*W1X(64+k0+1,col);
        } else {          // Wa (tgt)
            lo = ln_w[k0]*W1X(k0,col)     + ln_w[64+k0]*W1X(64+k0,col);
            hi = ln_w[k0+1]*W1X(k0+1,col) + ln_w[64+k0+1]*W1X(64+k0+1,col);
        }
        wsd[(sel ? WS_WAF : WS_WBF) + v2] = packbf2(lo, hi);
    } else if (bid == 8) {
        #pragma unroll
        for (int u0 = 0; u0 < 2; ++u0) {
            int u = u0*512 + tid;               // rc entries 0..1023
            int k = u >> 7, j = u & 127;
            float a = 0.f;
            #pragma unroll
            for (int i = 0; i < 8; ++i) a += rel[k*8+i] * ln_w[96+i] * W1X(96+i, j);
            ws[WS_RC + u] = a;
        }
    } else if (bid == 9) {
        if (tid < 128) {
            int u = 1024 + tid;                 // rc entries 1024..1151
            int k = u >> 7, j = u & 127;
            float a = 0.f;
            #pragma unroll
            for (int i = 0; i < 8; ++i) a += rel[k*8+i] * ln_w[96+i] * W1X(96+i, j);
            ws[WS_RC + u] = a;
        } else if (tid < 137) {
            int kk = tid - 128;
            float s = 0.f, sq = 0.f;
            #pragma unroll
            for (int i = 0; i < 8; ++i) { float v = rel[kk*8+i]; s += v; sq += v*v; }
            ws[WS_SR+kk] = s; ws[WS_SQR+kk] = sq;
        } else if (tid == 140) {
            ws[WS_SC] = sup_b2[0]; ws[WS_SC+1] = con_b2[0]; ws[WS_SC+2] = eml_bias[0];
        }
    } else {
        // S/T/W2: 4-way split over k
        int col = tid & 127, seg = tid >> 7;
        float S = 0.f, T = 0.f;
        for (int kk = seg*26; kk < seg*26 + 26; ++kk) {
            float w = W1X(kk, col);
            S += ln_w[kk]*w; T += ln_b[kk]*w;
        }
        pS[seg][col] = S; pT[seg][col] = T;
        __syncthreads();
        if (tid < 128) {
            float Tt = pT[0][tid] + pT[1][tid] + pT[2][tid] + pT[3][tid]
                       + (tid < 64 ? sup_b1[tid] : con_b1[tid-64]);
            ws[WS_S + tid]  = pS[0][tid] + pS[1][tid] + pS[2][tid] + pS[3][tid];
            ws[WS_T + tid]  = Tt * 32.f + 512.5f;     // pre-scaled for LUT quantize
            ws[WS_W2 + tid] = (tid < 64 ? sup_w2[tid] : con_w2[tid-64]);
        }
    }
}

// ---------------- main kernel: one 3x2 position tile per block (one-round grid) ----------------
__global__ __launch_bounds__(THREADS, 6) void eml_main(
    const float* __restrict__ hs, const float* __restrict__ act_in,
    const float* __restrict__ drive, const float* __restrict__ resist,
    float* __restrict__ out, const float* __restrict__ cst,
    float* __restrict__ part)
{
    __shared__ __align__(16) unsigned sB[80*68];    // 21760 B src@Wb bf16-pair
    __shared__ __align__(16) float    sA[24*132];   // 12672 B tgt@Wa f32
    __shared__ union __align__(16) UU {
        __hip_bfloat16 snb[80*40];                  // 6400 B (dead after stage 2)
        unsigned svcv[NROWS];                       // 3456 B (stage 3-4)
    } u;
    __shared__ __align__(16) float sdot[80*24];     // 7680 B [srow][ctr]
    __shared__ __align__(16) float sgelu[1024];     // 4096 B exact-GELU LUT, h=1/32
    __shared__ float sact[80], sSt[80], sSq[80];    // 960 B
    __shared__ float sSr[9], sSqr[9];               // 72 B

    const int tid = threadIdx.x;
    const int blk = blockIdx.x;
    const int b   = blk / 384;
    const int rm  = blk % 384;
    const int y0  = (rm / 16) * 2;   // 24 tiles along y
    const int x0  = (rm % 16) * 3;   // 16 tiles along x

    // ---- stage 0: GELU LUT ----
    #pragma unroll
    for (int i = tid; i < 1024; i += THREADS) {
        float x = (float)(i - 512) * 0.03125f;
        sgelu[i] = 0.5f * x * (1.0f + erff(x * 0.70710678118654752f));
    }

    // ---- stage 1: 80 halo vectors (4y x 5x positions x 4 hyp), 4 threads/vec ----
    if (tid < 320) {
        const int vec = tid >> 2, q = tid & 3;
        const int nb1 = vec >> 2, h1 = vec & 3;
        const int ny = nb1 / 5, nx = nb1 % 5;
        const int yy = y0 + ny - 1, xx = x0 + nx - 1;
        const bool vld = (yy >= 0) && (yy < SIDE) && (xx >= 0) && (xx < SIDE);
        const int npos = b*PPOS + yy*SIDE + xx;
        float4 v0 = make_float4(0.f,0.f,0.f,0.f), v1 = make_float4(0.f,0.f,0.f,0.f);
        if (vld) {
            const float4* p = reinterpret_cast<const float4*>(&hs[((size_t)npos*NHYP + h1)*FD + q*8]);
            v0 = p[0]; v1 = p[1];
        }
        unsigned* drow = reinterpret_cast<unsigned*>(&u.snb[vec*40]);
        drow[q*4+0] = packbf2(v0.x, v0.y);
        drow[q*4+1] = packbf2(v0.z, v0.w);
        drow[q*4+2] = packbf2(v1.x, v1.y);
        drow[q*4+3] = packbf2(v1.z, v1.w);
        float s  = (v0.x+v0.y+v0.z+v0.w) + (v1.x+v1.y+v1.z+v1.w);
        float sq = (v0.x*v0.x+v0.y*v0.y+v0.z*v0.z+v0.w*v0.w)
                 + (v1.x*v1.x+v1.y*v1.y+v1.z*v1.z+v1.w*v1.w);
        s += __shfl_xor(s, 1); sq += __shfl_xor(sq, 1);
        s += __shfl_xor(s, 2); sq += __shfl_xor(sq, 2);
        if (q == 0) {
            sSt[vec] = s; sSq[vec] = sq;
            sact[vec] = vld ? act_in[npos*NHYP + h1] : 0.f;
        }
    }
    if (tid < 9) { sSr[tid] = cst[WS_SR+tid]; sSqr[tid] = cst[WS_SQR+tid]; }
    __syncthreads();

    // ---- stage 2: MFMA GEMMs (8 waves) ----
    {
        const int wv = tid >> 6, lane = tid & 63;
        const int fr = lane & 15, fq = lane >> 4;
        const char* snbB = reinterpret_cast<const char*>(u.snb);
        U8 bB, bA;
        bB.u4 = reinterpret_cast<const uint4*>(cst + WS_WBF)[wv*64 + lane];
        bA.u4 = reinterpret_cast<const uint4*>(cst + WS_WAF)[wv*64 + lane];
        // G1: src (80 rows, 5 m-tiles) @ Wb -> sB bf16-pair
        #pragma unroll
        for (int m = 0; m < 5; ++m) {
            U8 a; a.u4 = *reinterpret_cast<const uint4*>(snbB + (m*16 + fr)*80 + fq*16);
            f32x4 acc = {0.f, 0.f, 0.f, 0.f};
            acc = __builtin_amdgcn_mfma_f32_16x16x32_bf16(a.s8, bB.s8, acc, 0, 0, 0);
            #pragma unroll
            for (int j = 0; j < 4; ++j) {
                float o = __shfl_xor(acc[j], 1);
                if (!(lane & 1))
                    sB[(m*16 + fq*4 + j)*68 + wv*8 + (fr >> 1)] = packbf2(acc[j], o);
            }
        }
        // tgt fragments: ctr t = pos*4+hh, pos = py*3+px; snb row = ((py+1)*5 + px+1)*4 + hh
        const int pos0 = fr >> 2, hh0 = fr & 3;
        const int trow0 = ((pos0/3 + 1)*5 + (pos0%3) + 1)*4 + hh0;
        int trow1 = 0;
        if (fr < 8) {
            const int t1 = 16 + fr, pos1 = t1 >> 2, hh1 = t1 & 3;
            trow1 = ((pos1/3 + 1)*5 + (pos1%3) + 1)*4 + hh1;
        }
        U8 at0, at1;
        at0.u4 = *reinterpret_cast<const uint4*>(snbB + trow0*80 + fq*16);
        at1.u4 = *reinterpret_cast<const uint4*>(snbB + trow1*80 + fq*16);
        // G2: tgt @ Wa -> sA f32 (24 rows)
        {
            f32x4 acc = {0.f, 0.f, 0.f, 0.f};
            acc = __builtin_amdgcn_mfma_f32_16x16x32_bf16(at0.s8, bA.s8, acc, 0, 0, 0);
            #pragma unroll
            for (int j = 0; j < 4; ++j)
                sA[(fq*4 + j)*132 + wv*16 + fr] = acc[j];
        }
        {
            f32x4 acc = {0.f, 0.f, 0.f, 0.f};
            acc = __builtin_amdgcn_mfma_f32_16x16x32_bf16(at1.s8, bA.s8, acc, 0, 0, 0);
            if (fq < 2) {
                #pragma unroll
                for (int j = 0; j < 4; ++j)
                    sA[(16 + fq*4 + j)*132 + wv*16 + fr] = acc[j];
            }
        }
        // G3: dot[src][ctr] = tgt @ src^T : 10 units (2 mt x 5 n) over 8 waves
        #pragma unroll
        for (int pass = 0; pass < 2; ++pass) {
            int uu = pass ? (8 + wv) : wv;
            if (pass && wv >= 2) break;
            const int mt = uu / 5, n = uu % 5;
            U8 sfr; sfr.u4 = *reinterpret_cast<const uint4*>(snbB + (n*16 + fr)*80 + fq*16);
            f32x4 acc = {0.f, 0.f, 0.f, 0.f};
            acc = __builtin_amdgcn_mfma_f32_16x16x32_bf16(mt ? at1.s8 : at0.s8, sfr.s8, acc, 0, 0, 0);
            if (!mt)
                *reinterpret_cast<f32x4*>(&sdot[(n*16 + fr)*24 + fq*4]) = acc;
            else if (fq < 2)
                *reinterpret_cast<f32x4*>(&sdot[(n*16 + fr)*24 + 16 + fq*4]) = acc;
        }
    }
    __syncthreads();

    // ---- stage 3: paired epilogue (432 units; 2 rows sharing pos,hh,k per thread) ----
    if (tid < 432) {
        const int pos = tid / 72, rr = tid % 72;
        const int hh = rr / 18, t2 = rr % 18;
        const int k  = t2 >> 1, hp = (t2 & 1) * 2;
        const int py = pos / 3, px = pos % 3;
        const int nbr  = (py + k/3)*5 + (px + k%3);
        const int srow0 = nbr*4 + hp;
        const int cidx = pos*4 + hh;
        const int crow = ((py + 1)*5 + px + 1)*4 + hh;
        const float gate0 = sact[srow0], gate1 = sact[srow0+1];
        const float dot0 = sdot[srow0*24 + cidx];
        const float dot1 = sdot[(srow0+1)*24 + cidx];
        const float Sqt2 = 2.f*sSq[crow];
        const float mu   = (2.f*sSt[crow] + sSr[k]) * (1.f/NJ);   // src terms cancel
        const float ss0  = Sqt2 + 2.f*sSq[srow0]   - 2.f*dot0 + sSqr[k];
        const float ss1  = Sqt2 + 2.f*sSq[srow0+1] - 2.f*dot1 + sSqr[k];
        const float rv0  = rsqrtf(ss0*(1.f/NJ) - mu*mu + 1e-5f);
        const float rv1  = rsqrtf(ss1*(1.f/NJ) - mu*mu + 1e-5f);
        const f32x2 r0_2 = {rv0*32.f, rv0*32.f};
        const f32x2 b0_2 = {-mu*rv0*32.f, -mu*rv0*32.f};
        const f32x2 r1_2 = {rv1*32.f, rv1*32.f};
        const f32x2 b1_2 = {-mu*rv1*32.f, -mu*rv1*32.f};
        const f32x2* a2 = reinterpret_cast<const f32x2*>(&sA[cidx*132]);
        const uint4* bR0 = reinterpret_cast<const uint4*>(&sB[srow0*68]);
        const uint4* bR1 = reinterpret_cast<const uint4*>(&sB[(srow0+1)*68]);
        const f32x2* c2 = reinterpret_cast<const f32x2*>(cst + WS_RC + k*128);
        const f32x2* S2 = reinterpret_cast<const f32x2*>(cst + WS_S);
        const f32x2* T2 = reinterpret_cast<const f32x2*>(cst + WS_T);
        float outs0 = 0.f, outc0 = 0.f, outs1 = 0.f, outc1 = 0.f;
        #pragma unroll 2
        for (int jq = 0; jq < 16; ++jq) {
            uint4 ub0 = bR0[jq];
            uint4 ub1 = bR1[jq];
            float acc0 = 0.f, acc1 = 0.f;
            #define PAIRQ(UW0, UW1, P) { \
                f32x2 ac = a2[jq*4+(P)] + c2[jq*4+(P)]; \
                f32x2 S_ = S2[jq*4+(P)], T_ = T2[jq*4+(P)]; \
                f32x2 C0 = b0_2*S_ + T_; \
                f32x2 C1 = b1_2*S_ + T_; \
                f32x2 bv0; bv0.x = bflo(UW0); bv0.y = bfhi(UW0); \
                f32x2 bv1; bv1.x = bflo(UW1); bv1.y = bfhi(UW1); \
                f32x2 q0 = r0_2*(ac + bv0) + C0; \
                f32x2 q1 = r1_2*(ac + bv1) + C1; \
                float w0 = cst[WS_W2 + jq*8 + 2*(P)]; \
                float w1 = cst[WS_W2 + jq*8 + 2*(P) + 1]; \
                acc0 = fmaf(sgelu[(unsigned)q0.x], w0, fmaf(sgelu[(unsigned)q0.y], w1, acc0)); \
                acc1 = fmaf(sgelu[(unsigned)q1.x], w0, fmaf(sgelu[(unsigned)q1.y], w1, acc1)); }
            PAIRQ(ub0.x, ub1.x, 0)
            PAIRQ(ub0.y, ub1.y, 1)
            PAIRQ(ub0.z, ub1.z, 2)
            PAIRQ(ub0.w, ub1.w, 3)
            #undef PAIRQ
            if (jq < 8) { outs0 += acc0; outs1 += acc1; }
            else        { outc0 += acc0; outc1 += acc1; }
        }
        const float b2s = cst[WS_SC], b2c = cst[WS_SC+1];
        const float sv0 = softplusf(outs0 + b2s), cv0 = softplusf(outc0 + b2c);
        const float sv1 = softplusf(outs1 + b2s), cv1 = softplusf(outc1 + b2c);
        const int obase = pos*144 + hh*36 + k*4 + hp;
        u.svcv[obase]   = packbf2(sv0*gate0, cv0*gate0);
        u.svcv[obase+1] = packbf2(sv1*gate1, cv1*gate1);
    }
    __syncthreads();

    // ---- stage 4: gated reduction + outputs + per-block partials ----
    float bl = 0.f, en = 0.f, ar = 0.f;
    if (tid < 96) {
        const int g = tid >> 2, qq = tid & 3;    // g = pos*4+hh
        const int pos4 = g >> 2, hh4 = g & 3;
        const int py = pos4 / 3, px = pos4 % 3;
        float svs = 0.f, cvs = 0.f, mass = 0.f;
        #pragma unroll
        for (int i = 0; i < 9; ++i) {
            int s = qq*9 + i;
            unsigned pp = u.svcv[pos4*144 + hh4*36 + s];
            svs += bflo(pp); cvs += bfhi(pp);
            int kk = s >> 2, h2 = s & 3;
            int nbr = (py + kk/3)*5 + (px + kk%3);
            mass += sact[nbr*4 + h2];
        }
        svs += __shfl_xor(svs, 1); cvs += __shfl_xor(cvs, 1); mass += __shfl_xor(mass, 1);
        svs += __shfl_xor(svs, 2); cvs += __shfl_xor(cvs, 2); mass += __shfl_xor(mass, 2);
        if (qq == 0) {
            mass = fmaxf(mass, 1e-6f);
            const float support  = svs / mass;
            const float conflict = cvs / mass;
            const int bph = (b*PPOS + (y0 + py)*SIDE + x0 + px)*NHYP + hh4;
            const float pd = drive[bph]  + support;
            const float pr = resist[bph] + conflict;
            float e = fminf(fmaxf(pd - pr + cst[WS_SC+2], -3.f), 3.f);
            const float a = 1.f / (1.f + expf(-e));
            out[0*NOUT + bph] = support;
            out[1*NOUT + bph] = conflict;
            out[2*NOUT + bph] = pd;
            out[3*NOUT + bph] = pr;
            out[4*NOUT + bph] = e;
            out[5*NOUT + bph] = a;
            out[6*NOUT + bph] = mass;
            bl = a;
            en = -(a*logf(a + 1e-8f) + (1.f - a)*logf(1.f - a + 1e-8f));
            ar = (a > 0.5f) ? 1.f : 0.f;
        }
    }
    if (tid < 128) {   // waves 0,1 fully active: safe shuffles; lanes>=96 carry zeros
        #pragma unroll
        for (int off = 32; off > 0; off >>= 1) {
            bl += __shfl_down(bl, off); en += __shfl_down(en, off); ar += __shfl_down(ar, off);
        }
        if ((tid & 63) == 0) {
            sdot[(tid >> 6)*4 + 0] = bl;
            sdot[(tid >> 6)*4 + 1] = en;
            sdot[(tid >> 6)*4 + 2] = ar;
        }
    }
    __syncthreads();
    if (tid == 0) {
        part[blk]          = sdot[0] + sdot[4];
        part[NBLK + blk]   = sdot[1] + sdot[5];
        part[2*NBLK + blk] = sdot[2] + sdot[6];
    }
}

// ---------------- final: reduce per-block partials ----------------
__global__ __launch_bounds__(256) void eml_final(const float* __restrict__ part, float* __restrict__ out3)
{
    __shared__ float red[4*3];
    float bl = 0.f, en = 0.f, ar = 0.f;
    for (int i = threadIdx.x; i < NBLK; i += 256) {
        bl += part[i];
        en += part[NBLK + i];
        ar += part[2*NBLK + i];
    }
    #pragma unroll
    for (int off = 32; off > 0; off >>= 1) {
        bl += __shfl_down(bl, off); en += __shfl_down(en, off); ar += __shfl_down(ar, off);
    }
    const int lane = threadIdx.x & 63, wid = threadIdx.x >> 6;
    if (lane == 0) { red[wid*3] = bl; red[wid*3+1] = en; red[wid*3+2] = ar; }
    __syncthreads();
    if (threadIdx.x == 0) {
        float b2 = 0.f, e2 = 0.f, a2 = 0.f;
        for (int w = 0; w < 4; ++w) { b2 += red[w*3]; e2 += red[w*3+1]; a2 += red[w*3+2]; }
        const float inv = 1.0f / (float)NOUT;
        out3[0] = b2*inv; out3[1] = e2*inv; out3[2] = a2*inv;
    }
}

extern "C" void kernel_launch(void* const* d_in, const int* in_sizes, int n_in,
                              void* d_out, int out_size, void* d_ws, size_t ws_size,
                              hipStream_t stream)
{
    (void)in_sizes; (void)n_in; (void)out_size; (void)ws_size;
    const float* hs    = (const float*)d_in[0];
    const float* act   = (const float*)d_in[1];
    const float* drv   = (const float*)d_in[2];
    const float* res   = (const float*)d_in[3];
    const float* rel   = (const float*)d_in[4];
    const float* lnw   = (const float*)d_in[5];
    const float* lnb   = (const float*)d_in[6];
    const float* sw1   = (const float*)d_in[7];
    const float* sb1   = (const float*)d_in[8];
    const float* sw2   = (const float*)d_in[9];
    const float* sb2   = (const float*)d_in[10];
    const float* cw1   = (const float*)d_in[11];
    const float* cb1   = (const float*)d_in[12];
    const float* cw2   = (const float*)d_in[13];
    const float* cb2   = (const float*)d_in[14];
    const float* ebias = (const float*)d_in[15];
    float* out = (float*)d_out;
    float* ws  = (float*)d_ws;

    eml_fold<<<dim3(11), dim3(512), 0, stream>>>(
        rel, lnw, lnb, sw1, sb1, sw2, sb2, cw1, cb1, cw2, cb2, ebias, ws);
    eml_main<<<dim3(NBLK), dim3(THREADS), 0, stream>>>(
        hs, act, drv, res, out, ws, ws + WS_PART);
    eml_final<<<dim3(1), dim3(256), 0, stream>>>(ws + WS_PART, out + 7*NOUT);
}

// Round 17
// 44.597 us; speedup vs baseline: 1.0189x; 1.0189x over previous
//
#include <hip/hip_runtime.h>
#include <hip/hip_bf16.h>
#include <math.h>

#define SIDE 48
#define PPOS (SIDE*SIDE)
#define NBATCH 2
#define NHYP 4
#define FD 32
#define RD 8
#define NJ 104
#define NBP (NBATCH*PPOS)       // 4608
#define NOUT (NBP*NHYP)         // 18432
#define THREADS 512
#define NROWS 864               // 6 positions x 144 rows
#define NBLK 768                // one-round grid: 3 blocks/CU x 256 CU
// d_ws dword offsets
#define WS_SR   16              // 9 f32
#define WS_SQR  28              // 9 f32
#define WS_SC   40              // 3 f32
#define WS_RC   64              // 9*128 f32
#define WS_S    1216            // 128 f32
#define WS_T    1344            // 128 f32 (pre-scaled: (T+b1)*32 + 512.5)
#define WS_W2   1472            // 128 f32
#define WS_WBF  1600            // 2048 dw
#define WS_WAF  3648            // 2048 dw
#define WS_PART 5696            // 3*NBLK f32

typedef __attribute__((ext_vector_type(8))) short short8;
typedef __attribute__((ext_vector_type(4))) float f32x4;
typedef __attribute__((ext_vector_type(2))) float f32x2;
union U8 { uint4 u4; short8 s8; };
union F4U { uint4 u; f32x2 h[2]; };

__device__ __forceinline__ float bflo(unsigned u) { return __uint_as_float(u << 16); }
__device__ __forceinline__ float bfhi(unsigned u) { return __uint_as_float(u & 0xffff0000u); }
__device__ __forceinline__ unsigned packbf2(float a, float b) {
    unsigned ua = __float_as_uint(a), ub = __float_as_uint(b);
    unsigned ra = (ua + 0x7fffu + ((ua >> 16) & 1u)) >> 16;
    unsigned rb = (ub + 0x7fffu + ((ub >> 16) & 1u)) & 0xffff0000u;
    return ra | rb;
}
__device__ __forceinline__ float softplusf(float v) {
    return fmaxf(v, 0.f) + log1pf(expf(-fabsf(v)));
}

#define W1X(kk, j) ((j) < 64 ? sup_w1[(kk)*64 + (j)] : con_w1[(kk)*64 + (j) - 64])

// ---------------- pre-kernel: fold weights once (11 blocks) ----------------
__global__ __launch_bounds__(512) void eml_fold(
    const float* __restrict__ rel, const float* __restrict__ ln_w, const float* __restrict__ ln_b,
    const float* __restrict__ sup_w1, const float* __restrict__ sup_b1,
    const float* __restrict__ sup_w2, const float* __restrict__ sup_b2,
    const float* __restrict__ con_w1, const float* __restrict__ con_b1,
    const float* __restrict__ con_w2, const float* __restrict__ con_b2,
    const float* __restrict__ eml_bias, float* __restrict__ ws)
{
    const int tid = threadIdx.x;
    const int bid = blockIdx.x;
    unsigned* wsd = reinterpret_cast<unsigned*>(ws);
    __shared__ float pS[4][128], pT[4][128];

    if (bid < 8) {
        // B-fragments: lane l holds W^T[col][k] pairs, k0=(l>>4)*8+2j
        int u = bid*512 + tid;
        int sel = u >> 11, v2 = u & 2047;
        int n = v2 >> 8, l = (v2 >> 2) & 63, j = v2 & 3;
        int k0 = (l >> 4)*8 + 2*j, col = n*16 + (l & 15);
        float lo, hi;
        if (sel == 0) {   // Wb (src)
            lo = ln_w[32+k0]*W1X(32+k0,col)     - ln_w[64+k0]*W1X(64+k0,col);
            hi = ln_w[32+k0+1]*W1X(32+k0+1,col) - ln_w[64+k0+1]*W1X(64+k0+1,col);
        } else {          // Wa (tgt)
            lo = ln_w[k0]*W1X(k0,col)     + ln_w[64+k0]*W1X(64+k0,col);
            hi = ln_w[k0+1]*W1X(k0+1,col) + ln_w[64+k0+1]*W1X(64+k0+1,col);
        }
        wsd[(sel ? WS_WAF : WS_WBF) + v2] = packbf2(lo, hi);
    } else if (bid == 8) {
        #pragma unroll
        for (int u0 = 0; u0 < 2; ++u0) {
            int u = u0*512 + tid;               // rc entries 0..1023
            int k = u >> 7, j = u & 127;
            float a = 0.f;
            #pragma unroll
            for (int i = 0; i < 8; ++i) a += rel[k*8+i] * ln_w[96+i] * W1X(96+i, j);
            ws[WS_RC + u] = a;
        }
    } else if (bid == 9) {
        if (tid < 128) {
            int u = 1024 + tid;                 // rc entries 1024..1151
            int k = u >> 7, j = u & 127;
            float a = 0.f;
            #pragma unroll
            for (int i = 0; i < 8; ++i) a += rel[k*8+i] * ln_w[96+i] * W1X(96+i, j);
            ws[WS_RC + u] = a;
        } else if (tid < 137) {
            int kk = tid - 128;
            float s = 0.f, sq = 0.f;
            #pragma unroll
            for (int i = 0; i < 8; ++i) { float v = rel[kk*8+i]; s += v; sq += v*v; }
            ws[WS_SR+kk] = s; ws[WS_SQR+kk] = sq;
        } else if (tid == 140) {
            ws[WS_SC] = sup_b2[0]; ws[WS_SC+1] = con_b2[0]; ws[WS_SC+2] = eml_bias[0];
        }
    } else {
        // S/T/W2: 4-way split over k
        int col = tid & 127, seg = tid >> 7;
        float S = 0.f, T = 0.f;
        for (int kk = seg*26; kk < seg*26 + 26; ++kk) {
            float w = W1X(kk, col);
            S += ln_w[kk]*w; T += ln_b[kk]*w;
        }
        pS[seg][col] = S; pT[seg][col] = T;
        __syncthreads();
        if (tid < 128) {
            float Tt = pT[0][tid] + pT[1][tid] + pT[2][tid] + pT[3][tid]
                       + (tid < 64 ? sup_b1[tid] : con_b1[tid-64]);
            ws[WS_S + tid]  = pS[0][tid] + pS[1][tid] + pS[2][tid] + pS[3][tid];
            ws[WS_T + tid]  = Tt * 32.f + 512.5f;     // pre-scaled for LUT quantize
            ws[WS_W2 + tid] = (tid < 64 ? sup_w2[tid] : con_w2[tid-64]);
        }
    }
}

// ---------------- main kernel: one 3x2 position tile per block (one-round grid) ----------------
__global__ __launch_bounds__(THREADS, 6) void eml_main(
    const float* __restrict__ hs, const float* __restrict__ act_in,
    const float* __restrict__ drive, const float* __restrict__ resist,
    float* __restrict__ out, const float* __restrict__ cst,
    float* __restrict__ part)
{
    __shared__ __align__(16) unsigned sB[80*68];    // 21760 B src@Wb bf16-pair
    __shared__ __align__(16) float    sA[24*132];   // 12672 B tgt@Wa f32
    __shared__ union __align__(16) UU {
        __hip_bfloat16 snb[80*40];                  // 6400 B (dead after stage 2)
        unsigned svcv[NROWS];                       // 3456 B (stage 3-4)
    } u;
    __shared__ __align__(16) float sdot[80*24];     // 7680 B [srow][ctr]
    __shared__ __align__(16) float sgelu[1024];     // 4096 B exact-GELU LUT, h=1/32
    __shared__ float sact[80], sSt[80], sSq[80];    // 960 B
    __shared__ float sSr[9], sSqr[9];               // 72 B

    const int tid = threadIdx.x;
    const int blk = blockIdx.x;
    const int b   = blk / 384;
    const int rm  = blk % 384;
    const int y0  = (rm / 16) * 2;   // 24 tiles along y
    const int x0  = (rm % 16) * 3;   // 16 tiles along x

    // ---- stage 0: GELU LUT ----
    #pragma unroll
    for (int i = tid; i < 1024; i += THREADS) {
        float x = (float)(i - 512) * 0.03125f;
        sgelu[i] = 0.5f * x * (1.0f + erff(x * 0.70710678118654752f));
    }

    // ---- stage 1: 80 halo vectors (4y x 5x positions x 4 hyp), 4 threads/vec ----
    if (tid < 320) {
        const int vec = tid >> 2, q = tid & 3;
        const int nb1 = vec >> 2, h1 = vec & 3;
        const int ny = nb1 / 5, nx = nb1 % 5;
        const int yy = y0 + ny - 1, xx = x0 + nx - 1;
        const bool vld = (yy >= 0) && (yy < SIDE) && (xx >= 0) && (xx < SIDE);
        const int npos = b*PPOS + yy*SIDE + xx;
        float4 v0 = make_float4(0.f,0.f,0.f,0.f), v1 = make_float4(0.f,0.f,0.f,0.f);
        if (vld) {
            const float4* p = reinterpret_cast<const float4*>(&hs[((size_t)npos*NHYP + h1)*FD + q*8]);
            v0 = p[0]; v1 = p[1];
        }
        unsigned* drow = reinterpret_cast<unsigned*>(&u.snb[vec*40]);
        drow[q*4+0] = packbf2(v0.x, v0.y);
        drow[q*4+1] = packbf2(v0.z, v0.w);
        drow[q*4+2] = packbf2(v1.x, v1.y);
        drow[q*4+3] = packbf2(v1.z, v1.w);
        float s  = (v0.x+v0.y+v0.z+v0.w) + (v1.x+v1.y+v1.z+v1.w);
        float sq = (v0.x*v0.x+v0.y*v0.y+v0.z*v0.z+v0.w*v0.w)
                 + (v1.x*v1.x+v1.y*v1.y+v1.z*v1.z+v1.w*v1.w);
        s += __shfl_xor(s, 1); sq += __shfl_xor(sq, 1);
        s += __shfl_xor(s, 2); sq += __shfl_xor(sq, 2);
        if (q == 0) {
            sSt[vec] = s; sSq[vec] = sq;
            sact[vec] = vld ? act_in[npos*NHYP + h1] : 0.f;
        }
    }
    if (tid < 9) { sSr[tid] = cst[WS_SR+tid]; sSqr[tid] = cst[WS_SQR+tid]; }
    __syncthreads();

    // ---- stage 2: MFMA GEMMs (8 waves) ----
    {
        const int wv = tid >> 6, lane = tid & 63;
        const int fr = lane & 15, fq = lane >> 4;
        const char* snbB = reinterpret_cast<const char*>(u.snb);
        U8 bB, bA;
        bB.u4 = reinterpret_cast<const uint4*>(cst + WS_WBF)[wv*64 + lane];
        bA.u4 = reinterpret_cast<const uint4*>(cst + WS_WAF)[wv*64 + lane];
        // G1: src (80 rows, 5 m-tiles) @ Wb -> sB bf16-pair
        #pragma unroll
        for (int m = 0; m < 5; ++m) {
            U8 a; a.u4 = *reinterpret_cast<const uint4*>(snbB + (m*16 + fr)*80 + fq*16);
            f32x4 acc = {0.f, 0.f, 0.f, 0.f};
            acc = __builtin_amdgcn_mfma_f32_16x16x32_bf16(a.s8, bB.s8, acc, 0, 0, 0);
            #pragma unroll
            for (int j = 0; j < 4; ++j) {
                float o = __shfl_xor(acc[j], 1);
                if (!(lane & 1))
                    sB[(m*16 + fq*4 + j)*68 + wv*8 + (fr >> 1)] = packbf2(acc[j], o);
            }
        }
        // tgt fragments: ctr t = pos*4+hh, pos = py*3+px; snb row = ((py+1)*5 + px+1)*4 + hh
        const int pos0 = fr >> 2, hh0 = fr & 3;
        const int trow0 = ((pos0/3 + 1)*5 + (pos0%3) + 1)*4 + hh0;
        int trow1 = 0;
        if (fr < 8) {
            const int t1 = 16 + fr, pos1 = t1 >> 2, hh1 = t1 & 3;
            trow1 = ((pos1/3 + 1)*5 + (pos1%3) + 1)*4 + hh1;
        }
        U8 at0, at1;
        at0.u4 = *reinterpret_cast<const uint4*>(snbB + trow0*80 + fq*16);
        at1.u4 = *reinterpret_cast<const uint4*>(snbB + trow1*80 + fq*16);
        // G2: tgt @ Wa -> sA f32 (24 rows)
        {
            f32x4 acc = {0.f, 0.f, 0.f, 0.f};
            acc = __builtin_amdgcn_mfma_f32_16x16x32_bf16(at0.s8, bA.s8, acc, 0, 0, 0);
            #pragma unroll
            for (int j = 0; j < 4; ++j)
                sA[(fq*4 + j)*132 + wv*16 + fr] = acc[j];
        }
        {
            f32x4 acc = {0.f, 0.f, 0.f, 0.f};
            acc = __builtin_amdgcn_mfma_f32_16x16x32_bf16(at1.s8, bA.s8, acc, 0, 0, 0);
            if (fq < 2) {
                #pragma unroll
                for (int j = 0; j < 4; ++j)
                    sA[(16 + fq*4 + j)*132 + wv*16 + fr] = acc[j];
            }
        }
        // G3: dot[src][ctr] = tgt @ src^T : 10 units (2 mt x 5 n) over 8 waves
        #pragma unroll
        for (int pass = 0; pass < 2; ++pass) {
            int uu = pass ? (8 + wv) : wv;
            if (pass && wv >= 2) break;
            const int mt = uu / 5, n = uu % 5;
            U8 sfr; sfr.u4 = *reinterpret_cast<const uint4*>(snbB + (n*16 + fr)*80 + fq*16);
            f32x4 acc = {0.f, 0.f, 0.f, 0.f};
            acc = __builtin_amdgcn_mfma_f32_16x16x32_bf16(mt ? at1.s8 : at0.s8, sfr.s8, acc, 0, 0, 0);
            if (!mt)
                *reinterpret_cast<f32x4*>(&sdot[(n*16 + fr)*24 + fq*4]) = acc;
            else if (fq < 2)
                *reinterpret_cast<f32x4*>(&sdot[(n*16 + fr)*24 + 16 + fq*4]) = acc;
        }
    }
    __syncthreads();

    // ---- stage 3: per-row epilogue (864 rows; b128 a/c loads; f32x2 math; LUT) ----
    for (int ri = tid; ri < NROWS; ri += THREADS) {
        const int pos = ri / 144, r = ri % 144;
        const int hh = r / 36, s = r % 36, k = s >> 2, h2 = s & 3;
        const int py = pos / 3, px = pos % 3;
        const int nbr  = (py + k/3)*5 + (px + k%3);
        const int srow = nbr*4 + h2;
        const float gate = sact[srow];
        float svv = 0.f, cvv = 0.f;
        if (gate > 0.f) {
            const int cidx = pos*4 + hh;
            const int crow = ((py + 1)*5 + px + 1)*4 + hh;
            const float dot = sdot[srow*24 + cidx];
            const float mu   = (2.f*sSt[crow] + sSr[k]) * (1.f/NJ);
            const float ssum = 2.f*sSq[crow] + 2.f*sSq[srow] - 2.f*dot + sSqr[k];
            const float rinv = rsqrtf(ssum*(1.f/NJ) - mu*mu + 1e-5f);
            const float r32  = rinv * 32.f;
            const float b32  = -mu * r32;
            const f32x2 r32_2 = {r32, r32};
            const f32x2 b32_2 = {b32, b32};
            const uint4* aR4 = reinterpret_cast<const uint4*>(&sA[cidx*132]);
            const uint4* bR  = reinterpret_cast<const uint4*>(&sB[srow*68]);
            const uint4* cR4 = reinterpret_cast<const uint4*>(cst + WS_RC + k*128);
            const f32x2* S2  = reinterpret_cast<const f32x2*>(cst + WS_S);
            const f32x2* T2  = reinterpret_cast<const f32x2*>(cst + WS_T);
            float outs = 0.f, outc = 0.f;
            #pragma unroll 2
            for (int jq = 0; jq < 16; ++jq) {
                uint4 ub = bR[jq];
                F4U a0; a0.u = aR4[jq*2];
                F4U a1; a1.u = aR4[jq*2+1];
                F4U c0; c0.u = cR4[jq*2];
                F4U c1; c1.u = cR4[jq*2+1];
                float accv = 0.f;
                #define PAIR(UW, AV, CV, P) { \
                    f32x2 bv; bv.x = bflo(UW); bv.y = bfhi(UW); \
                    f32x2 d  = AV + bv + CV; \
                    f32x2 qv = r32_2*d + (b32_2*S2[jq*4+(P)] + T2[jq*4+(P)]); \
                    float g0 = sgelu[(unsigned)qv.x]; \
                    float g1 = sgelu[(unsigned)qv.y]; \
                    accv = fmaf(g0, cst[WS_W2 + jq*8 + 2*(P)], accv); \
                    accv = fmaf(g1, cst[WS_W2 + jq*8 + 2*(P) + 1], accv); }
                PAIR(ub.x, a0.h[0], c0.h[0], 0)
                PAIR(ub.y, a0.h[1], c0.h[1], 1)
                PAIR(ub.z, a1.h[0], c1.h[0], 2)
                PAIR(ub.w, a1.h[1], c1.h[1], 3)
                #undef PAIR
                if (jq < 8) outs += accv; else outc += accv;
            }
            svv = softplusf(outs + cst[WS_SC]);
            cvv = softplusf(outc + cst[WS_SC+1]);
        }
        u.svcv[ri] = packbf2(svv*gate, cvv*gate);
    }
    __syncthreads();

    // ---- stage 4: gated reduction + outputs + per-block partials ----
    float bl = 0.f, en = 0.f, ar = 0.f;
    if (tid < 96) {
        const int g = tid >> 2, qq = tid & 3;    // g = pos*4+hh
        const int pos4 = g >> 2, hh4 = g & 3;
        const int py = pos4 / 3, px = pos4 % 3;
        float svs = 0.f, cvs = 0.f, mass = 0.f;
        #pragma unroll
        for (int i = 0; i < 9; ++i) {
            int s = qq*9 + i;
            unsigned pp = u.svcv[pos4*144 + hh4*36 + s];
            svs += bflo(pp); cvs += bfhi(pp);
            int kk = s >> 2, h2 = s & 3;
            int nbr = (py + kk/3)*5 + (px + kk%3);
            mass += sact[nbr*4 + h2];
        }
        svs += __shfl_xor(svs, 1); cvs += __shfl_xor(cvs, 1); mass += __shfl_xor(mass, 1);
        svs += __shfl_xor(svs, 2); cvs += __shfl_xor(cvs, 2); mass += __shfl_xor(mass, 2);
        if (qq == 0) {
            mass = fmaxf(mass, 1e-6f);
            const float support  = svs / mass;
            const float conflict = cvs / mass;
            const int bph = (b*PPOS + (y0 + py)*SIDE + x0 + px)*NHYP + hh4;
            const float pd = drive[bph]  + support;
            const float pr = resist[bph] + conflict;
            float e = fminf(fmaxf(pd - pr + cst[WS_SC+2], -3.f), 3.f);
            const float a = 1.f / (1.f + expf(-e));
            out[0*NOUT + bph] = support;
            out[1*NOUT + bph] = conflict;
            out[2*NOUT + bph] = pd;
            out[3*NOUT + bph] = pr;
            out[4*NOUT + bph] = e;
            out[5*NOUT + bph] = a;
            out[6*NOUT + bph] = mass;
            bl = a;
            en = -(a*logf(a + 1e-8f) + (1.f - a)*logf(1.f - a + 1e-8f));
            ar = (a > 0.5f) ? 1.f : 0.f;
        }
    }
    if (tid < 128) {   // waves 0,1 fully active: safe shuffles; lanes>=96 carry zeros
        #pragma unroll
        for (int off = 32; off > 0; off >>= 1) {
            bl += __shfl_down(bl, off); en += __shfl_down(en, off); ar += __shfl_down(ar, off);
        }
        if ((tid & 63) == 0) {
            sdot[(tid >> 6)*4 + 0] = bl;
            sdot[(tid >> 6)*4 + 1] = en;
            sdot[(tid >> 6)*4 + 2] = ar;
        }
    }
    __syncthreads();
    if (tid == 0) {
        part[blk]          = sdot[0] + sdot[4];
        part[NBLK + blk]   = sdot[1] + sdot[5];
        part[2*NBLK + blk] = sdot[2] + sdot[6];
    }
}

// ---------------- final: reduce per-block partials ----------------
__global__ __launch_bounds__(256) void eml_final(const float* __restrict__ part, float* __restrict__ out3)
{
    __shared__ float red[4*3];
    float bl = 0.f, en = 0.f, ar = 0.f;
    for (int i = threadIdx.x; i < NBLK; i += 256) {
        bl += part[i];
        en += part[NBLK + i];
        ar += part[2*NBLK + i];
    }
    #pragma unroll
    for (int off = 32; off > 0; off >>= 1) {
        bl += __shfl_down(bl, off); en += __shfl_down(en, off); ar += __shfl_down(ar, off);
    }
    const int lane = threadIdx.x & 63, wid = threadIdx.x >> 6;
    if (lane == 0) { red[wid*3] = bl; red[wid*3+1] = en; red[wid*3+2] = ar; }
    __syncthreads();
    if (threadIdx.x == 0) {
        float b2 = 0.f, e2 = 0.f, a2 = 0.f;
        for (int w = 0; w < 4; ++w) { b2 += red[w*3]; e2 += red[w*3+1]; a2 += red[w*3+2]; }
        const float inv = 1.0f / (float)NOUT;
        out3[0] = b2*inv; out3[1] = e2*inv; out3[2] = a2*inv;
    }
}

extern "C" void kernel_launch(void* const* d_in, const int* in_sizes, int n_in,
                              void* d_out, int out_size, void* d_ws, size_t ws_size,
                              hipStream_t stream)
{
    (void)in_sizes; (void)n_in; (void)out_size; (void)ws_size;
    const float* hs    = (const float*)d_in[0];
    const float* act   = (const float*)d_in[1];
    const float* drv   = (const float*)d_in[2];
    const float* res   = (const float*)d_in[3];
    const float* rel   = (const float*)d_in[4];
    const float* lnw   = (const float*)d_in[5];
    const float* lnb   = (const float*)d_in[6];
    const float* sw1   = (const float*)d_in[7];
    const float* sb1   = (const float*)d_in[8];
    const float* sw2   = (const float*)d_in[9];
    const float* sb2   = (const float*)d_in[10];
    const float* cw1   = (const float*)d_in[11];
    const float* cb1   = (const float*)d_in[12];
    const float* cw2   = (const float*)d_in[13];
    const float* cb2   = (const float*)d_in[14];
    const float* ebias = (const float*)d_in[15];
    float* out = (float*)d_out;
    float* ws  = (float*)d_ws;

    eml_fold<<<dim3(11), dim3(512), 0, stream>>>(
        rel, lnw, lnb, sw1, sb1, sw2, sb2, cw1, cb1, cw2, cb2, ebias, ws);
    eml_main<<<dim3(NBLK), dim3(THREADS), 0, stream>>>(
        hs, act, drv, res, out, ws, ws + WS_PART);
    eml_final<<<dim3(1), dim3(256), 0, stream>>>(ws + WS_PART, out + 7*NOUT);
}

// Round 18
// 44.309 us; speedup vs baseline: 1.0255x; 1.0065x over previous
//
#include <hip/hip_runtime.h>
#include <hip/hip_bf16.h>
#include <math.h>

#define SIDE 48
#define PPOS (SIDE*SIDE)
#define NBATCH 2
#define NHYP 4
#define FD 32
#define RD 8
#define NJ 104
#define NBP (NBATCH*PPOS)       // 4608
#define NOUT (NBP*NHYP)         // 18432
#define THREADS 512
#define NROWS 864               // 6 positions x 144 rows
#define NBLK 768                // one-round grid: 3 blocks/CU x 256 CU
// d_ws dword offsets
#define WS_SR   16              // 9 f32
#define WS_SQR  28              // 9 f32
#define WS_SC   40              // 3 f32
#define WS_RC   64              // 9*128 f32
#define WS_S    1216            // 128 f32
#define WS_T    1344            // 128 f32 (pre-scaled: (T+b1)*32 + 512.5)
#define WS_W2   1472            // 128 f32
#define WS_WBF  1600            // 2048 dw
#define WS_WAF  3648            // 2048 dw
#define WS_PART 5696            // 3*NBLK f32
#define WS_LUT  8000            // 1024 f32 GELU LUT

typedef __attribute__((ext_vector_type(8))) short short8;
typedef __attribute__((ext_vector_type(4))) float f32x4;
typedef __attribute__((ext_vector_type(2))) float f32x2;
union U8 { uint4 u4; short8 s8; };
union F4U { uint4 u; f32x2 h[2]; };

__device__ __forceinline__ float bflo(unsigned u) { return __uint_as_float(u << 16); }
__device__ __forceinline__ float bfhi(unsigned u) { return __uint_as_float(u & 0xffff0000u); }
__device__ __forceinline__ unsigned packbf2(float a, float b) {
    unsigned ua = __float_as_uint(a), ub = __float_as_uint(b);
    unsigned ra = (ua + 0x7fffu + ((ua >> 16) & 1u)) >> 16;
    unsigned rb = (ub + 0x7fffu + ((ub >> 16) & 1u)) & 0xffff0000u;
    return ra | rb;
}
__device__ __forceinline__ float softplusf(float v) {
    return fmaxf(v, 0.f) + log1pf(expf(-fabsf(v)));
}

#define W1X(kk, j) ((j) < 64 ? sup_w1[(kk)*64 + (j)] : con_w1[(kk)*64 + (j) - 64])

// ---------------- pre-kernel: fold weights once (12 blocks) ----------------
__global__ __launch_bounds__(512) void eml_fold(
    const float* __restrict__ rel, const float* __restrict__ ln_w, const float* __restrict__ ln_b,
    const float* __restrict__ sup_w1, const float* __restrict__ sup_b1,
    const float* __restrict__ sup_w2, const float* __restrict__ sup_b2,
    const float* __restrict__ con_w1, const float* __restrict__ con_b1,
    const float* __restrict__ con_w2, const float* __restrict__ con_b2,
    const float* __restrict__ eml_bias, float* __restrict__ ws)
{
    const int tid = threadIdx.x;
    const int bid = blockIdx.x;
    unsigned* wsd = reinterpret_cast<unsigned*>(ws);
    __shared__ float pS[4][128], pT[4][128];

    if (bid < 8) {
        // B-fragments: lane l holds W^T[col][k] pairs, k0=(l>>4)*8+2j
        int u = bid*512 + tid;
        int sel = u >> 11, v2 = u & 2047;
        int n = v2 >> 8, l = (v2 >> 2) & 63, j = v2 & 3;
        int k0 = (l >> 4)*8 + 2*j, col = n*16 + (l & 15);
        float lo, hi;
        if (sel == 0) {   // Wb (src)
            lo = ln_w[32+k0]*W1X(32+k0,col)     - ln_w[64+k0]*W1X(64+k0,col);
            hi = ln_w[32+k0+1]*W1X(32+k0+1,col) - ln_w[64+k0+1]*W1X(64+k0+1,col);
        } else {          // Wa (tgt)
            lo = ln_w[k0]*W1X(k0,col)     + ln_w[64+k0]*W1X(64+k0,col);
            hi = ln_w[k0+1]*W1X(k0+1,col) + ln_w[64+k0+1]*W1X(64+k0+1,col);
        }
        wsd[(sel ? WS_WAF : WS_WBF) + v2] = packbf2(lo, hi);
    } else if (bid == 8) {
        #pragma unroll
        for (int u0 = 0; u0 < 2; ++u0) {
            int u = u0*512 + tid;               // rc entries 0..1023
            int k = u >> 7, j = u & 127;
            float a = 0.f;
            #pragma unroll
            for (int i = 0; i < 8; ++i) a += rel[k*8+i] * ln_w[96+i] * W1X(96+i, j);
            ws[WS_RC + u] = a;
        }
    } else if (bid == 9) {
        if (tid < 128) {
            int u = 1024 + tid;                 // rc entries 1024..1151
            int k = u >> 7, j = u & 127;
            float a = 0.f;
            #pragma unroll
            for (int i = 0; i < 8; ++i) a += rel[k*8+i] * ln_w[96+i] * W1X(96+i, j);
            ws[WS_RC + u] = a;
        } else if (tid < 137) {
            int kk = tid - 128;
            float s = 0.f, sq = 0.f;
            #pragma unroll
            for (int i = 0; i < 8; ++i) { float v = rel[kk*8+i]; s += v; sq += v*v; }
            ws[WS_SR+kk] = s; ws[WS_SQR+kk] = sq;
        } else if (tid == 140) {
            ws[WS_SC] = sup_b2[0]; ws[WS_SC+1] = con_b2[0]; ws[WS_SC+2] = eml_bias[0];
        }
    } else if (bid == 11) {
        // exact GELU LUT over [-16,16), h = 1/32
        #pragma unroll
        for (int u0 = 0; u0 < 2; ++u0) {
            int i = u0*512 + tid;
            float x = (float)(i - 512) * 0.03125f;
            ws[WS_LUT + i] = 0.5f * x * (1.0f + erff(x * 0.70710678118654752f));
        }
    } else {
        // S/T/W2: 4-way split over k
        int col = tid & 127, seg = tid >> 7;
        float S = 0.f, T = 0.f;
        for (int kk = seg*26; kk < seg*26 + 26; ++kk) {
            float w = W1X(kk, col);
            S += ln_w[kk]*w; T += ln_b[kk]*w;
        }
        pS[seg][col] = S; pT[seg][col] = T;
        __syncthreads();
        if (tid < 128) {
            float Tt = pT[0][tid] + pT[1][tid] + pT[2][tid] + pT[3][tid]
                       + (tid < 64 ? sup_b1[tid] : con_b1[tid-64]);
            ws[WS_S + tid]  = pS[0][tid] + pS[1][tid] + pS[2][tid] + pS[3][tid];
            ws[WS_T + tid]  = Tt * 32.f + 512.5f;     // pre-scaled for LUT quantize
            ws[WS_W2 + tid] = (tid < 64 ? sup_w2[tid] : con_w2[tid-64]);
        }
    }
}

// ---------------- main kernel: one 3x2 position tile per block (one-round grid) ----------------
__global__ __launch_bounds__(THREADS, 6) void eml_main(
    const float* __restrict__ hs, const float* __restrict__ act_in,
    const float* __restrict__ drive, const float* __restrict__ resist,
    float* __restrict__ out, const float* __restrict__ cst,
    float* __restrict__ part)
{
    __shared__ __align__(16) unsigned sB[80*68];    // 21760 B src@Wb bf16-pair
    __shared__ __align__(16) float    sA[24*132];   // 12672 B tgt@Wa f32
    __shared__ union __align__(16) UU {
        __hip_bfloat16 snb[80*40];                  // 6400 B (dead after stage 2)
        unsigned svcv[NROWS];                       // 3456 B (stage 3-4)
    } u;
    __shared__ __align__(16) float sdot[80*24];     // 7680 B [srow][ctr]
    __shared__ __align__(16) float sgelu[1024];     // 4096 B exact-GELU LUT, h=1/32
    __shared__ float sact[80], sSt[80], sSq[80];    // 960 B
    __shared__ float sSr[9], sSqr[9];               // 72 B

    const int tid = threadIdx.x;
    const int blk = blockIdx.x;
    const int b   = blk / 384;
    const int rm  = blk % 384;
    const int y0  = (rm / 16) * 2;   // 24 tiles along y
    const int x0  = (rm % 16) * 3;   // 16 tiles along x

    // ---- stage 0: copy GELU LUT from workspace ----
    #pragma unroll
    for (int i = tid; i < 1024; i += THREADS)
        sgelu[i] = cst[WS_LUT + i];

    // ---- stage 1: 80 halo vectors (4y x 5x positions x 4 hyp), 4 threads/vec ----
    if (tid < 320) {
        const int vec = tid >> 2, q = tid & 3;
        const int nb1 = vec >> 2, h1 = vec & 3;
        const int ny = nb1 / 5, nx = nb1 % 5;
        const int yy = y0 + ny - 1, xx = x0 + nx - 1;
        const bool vld = (yy >= 0) && (yy < SIDE) && (xx >= 0) && (xx < SIDE);
        const int npos = b*PPOS + yy*SIDE + xx;
        float4 v0 = make_float4(0.f,0.f,0.f,0.f), v1 = make_float4(0.f,0.f,0.f,0.f);
        if (vld) {
            const float4* p = reinterpret_cast<const float4*>(&hs[((size_t)npos*NHYP + h1)*FD + q*8]);
            v0 = p[0]; v1 = p[1];
        }
        unsigned* drow = reinterpret_cast<unsigned*>(&u.snb[vec*40]);
        drow[q*4+0] = packbf2(v0.x, v0.y);
        drow[q*4+1] = packbf2(v0.z, v0.w);
        drow[q*4+2] = packbf2(v1.x, v1.y);
        drow[q*4+3] = packbf2(v1.z, v1.w);
        float s  = (v0.x+v0.y+v0.z+v0.w) + (v1.x+v1.y+v1.z+v1.w);
        float sq = (v0.x*v0.x+v0.y*v0.y+v0.z*v0.z+v0.w*v0.w)
                 + (v1.x*v1.x+v1.y*v1.y+v1.z*v1.z+v1.w*v1.w);
        s += __shfl_xor(s, 1); sq += __shfl_xor(sq, 1);
        s += __shfl_xor(s, 2); sq += __shfl_xor(sq, 2);
        if (q == 0) {
            sSt[vec] = s; sSq[vec] = sq;
            sact[vec] = vld ? act_in[npos*NHYP + h1] : 0.f;
        }
    }
    if (tid < 9) { sSr[tid] = cst[WS_SR+tid]; sSqr[tid] = cst[WS_SQR+tid]; }
    __syncthreads();

    // ---- stage 2: MFMA GEMMs (8 waves) ----
    {
        const int wv = tid >> 6, lane = tid & 63;
        const int fr = lane & 15, fq = lane >> 4;
        const char* snbB = reinterpret_cast<const char*>(u.snb);
        U8 bB, bA;
        bB.u4 = reinterpret_cast<const uint4*>(cst + WS_WBF)[wv*64 + lane];
        bA.u4 = reinterpret_cast<const uint4*>(cst + WS_WAF)[wv*64 + lane];
        // G1: src (80 rows, 5 m-tiles) @ Wb -> sB bf16-pair
        #pragma unroll
        for (int m = 0; m < 5; ++m) {
            U8 a; a.u4 = *reinterpret_cast<const uint4*>(snbB + (m*16 + fr)*80 + fq*16);
            f32x4 acc = {0.f, 0.f, 0.f, 0.f};
            acc = __builtin_amdgcn_mfma_f32_16x16x32_bf16(a.s8, bB.s8, acc, 0, 0, 0);
            #pragma unroll
            for (int j = 0; j < 4; ++j) {
                float o = __shfl_xor(acc[j], 1);
                if (!(lane & 1))
                    sB[(m*16 + fq*4 + j)*68 + wv*8 + (fr >> 1)] = packbf2(acc[j], o);
            }
        }
        // tgt fragments: ctr t = pos*4+hh, pos = py*3+px; snb row = ((py+1)*5 + px+1)*4 + hh
        const int pos0 = fr >> 2, hh0 = fr & 3;
        const int trow0 = ((pos0/3 + 1)*5 + (pos0%3) + 1)*4 + hh0;
        int trow1 = 0;
        if (fr < 8) {
            const int t1 = 16 + fr, pos1 = t1 >> 2, hh1 = t1 & 3;
            trow1 = ((pos1/3 + 1)*5 + (pos1%3) + 1)*4 + hh1;
        }
        U8 at0, at1;
        at0.u4 = *reinterpret_cast<const uint4*>(snbB + trow0*80 + fq*16);
        at1.u4 = *reinterpret_cast<const uint4*>(snbB + trow1*80 + fq*16);
        // G2: tgt @ Wa -> sA f32 (24 rows)
        {
            f32x4 acc = {0.f, 0.f, 0.f, 0.f};
            acc = __builtin_amdgcn_mfma_f32_16x16x32_bf16(at0.s8, bA.s8, acc, 0, 0, 0);
            #pragma unroll
            for (int j = 0; j < 4; ++j)
                sA[(fq*4 + j)*132 + wv*16 + fr] = acc[j];
        }
        {
            f32x4 acc = {0.f, 0.f, 0.f, 0.f};
            acc = __builtin_amdgcn_mfma_f32_16x16x32_bf16(at1.s8, bA.s8, acc, 0, 0, 0);
            if (fq < 2) {
                #pragma unroll
                for (int j = 0; j < 4; ++j)
                    sA[(16 + fq*4 + j)*132 + wv*16 + fr] = acc[j];
            }
        }
        // G3: dot[src][ctr] = tgt @ src^T : 10 units (2 mt x 5 n) over 8 waves
        #pragma unroll
        for (int pass = 0; pass < 2; ++pass) {
            int uu = pass ? (8 + wv) : wv;
            if (pass && wv >= 2) break;
            const int mt = uu / 5, n = uu % 5;
            U8 sfr; sfr.u4 = *reinterpret_cast<const uint4*>(snbB + (n*16 + fr)*80 + fq*16);
            f32x4 acc = {0.f, 0.f, 0.f, 0.f};
            acc = __builtin_amdgcn_mfma_f32_16x16x32_bf16(mt ? at1.s8 : at0.s8, sfr.s8, acc, 0, 0, 0);
            if (!mt)
                *reinterpret_cast<f32x4*>(&sdot[(n*16 + fr)*24 + fq*4]) = acc;
            else if (fq < 2)
                *reinterpret_cast<f32x4*>(&sdot[(n*16 + fr)*24 + 16 + fq*4]) = acc;
        }
    }
    __syncthreads();

    // ---- stage 3: per-row epilogue (864 rows; b128 a/c loads; f32x2 math; LUT) ----
    for (int ri = tid; ri < NROWS; ri += THREADS) {
        const int pos = ri / 144, r = ri % 144;
        const int hh = r / 36, s = r % 36, k = s >> 2, h2 = s & 3;
        const int py = pos / 3, px = pos % 3;
        const int nbr  = (py + k/3)*5 + (px + k%3);
        const int srow = nbr*4 + h2;
        const float gate = sact[srow];
        float svv = 0.f, cvv = 0.f;
        if (gate > 0.f) {
            const int cidx = pos*4 + hh;
            const int crow = ((py + 1)*5 + px + 1)*4 + hh;
            const float dot = sdot[srow*24 + cidx];
            const float mu   = (2.f*sSt[crow] + sSr[k]) * (1.f/NJ);
            const float ssum = 2.f*sSq[crow] + 2.f*sSq[srow] - 2.f*dot + sSqr[k];
            const float rinv = rsqrtf(ssum*(1.f/NJ) - mu*mu + 1e-5f);
            const float r32  = rinv * 32.f;
            const float b32  = -mu * r32;
            const f32x2 r32_2 = {r32, r32};
            const f32x2 b32_2 = {b32, b32};
            const uint4* aR4 = reinterpret_cast<const uint4*>(&sA[cidx*132]);
            const uint4* bR  = reinterpret_cast<const uint4*>(&sB[srow*68]);
            const uint4* cR4 = reinterpret_cast<const uint4*>(cst + WS_RC + k*128);
            const f32x2* S2  = reinterpret_cast<const f32x2*>(cst + WS_S);
            const f32x2* T2  = reinterpret_cast<const f32x2*>(cst + WS_T);
            float outs = 0.f, outc = 0.f;
            #pragma unroll 2
            for (int jq = 0; jq < 16; ++jq) {
                uint4 ub = bR[jq];
                F4U a0; a0.u = aR4[jq*2];
                F4U a1; a1.u = aR4[jq*2+1];
                F4U c0; c0.u = cR4[jq*2];
                F4U c1; c1.u = cR4[jq*2+1];
                float accv = 0.f;
                #define PAIR(UW, AV, CV, P) { \
                    f32x2 bv; bv.x = bflo(UW); bv.y = bfhi(UW); \
                    f32x2 d  = AV + bv + CV; \
                    f32x2 qv = r32_2*d + (b32_2*S2[jq*4+(P)] + T2[jq*4+(P)]); \
                    float g0 = sgelu[(unsigned)qv.x]; \
                    float g1 = sgelu[(unsigned)qv.y]; \
                    accv = fmaf(g0, cst[WS_W2 + jq*8 + 2*(P)], accv); \
                    accv = fmaf(g1, cst[WS_W2 + jq*8 + 2*(P) + 1], accv); }
                PAIR(ub.x, a0.h[0], c0.h[0], 0)
                PAIR(ub.y, a0.h[1], c0.h[1], 1)
                PAIR(ub.z, a1.h[0], c1.h[0], 2)
                PAIR(ub.w, a1.h[1], c1.h[1], 3)
                #undef PAIR
                if (jq < 8) outs += accv; else outc += accv;
            }
            svv = softplusf(outs + cst[WS_SC]);
            cvv = softplusf(outc + cst[WS_SC+1]);
        }
        u.svcv[ri] = packbf2(svv*gate, cvv*gate);
    }
    __syncthreads();

    // ---- stage 4: gated reduction + outputs + per-block partials ----
    float bl = 0.f, en = 0.f, ar = 0.f;
    if (tid < 96) {
        const int g = tid >> 2, qq = tid & 3;    // g = pos*4+hh
        const int pos4 = g >> 2, hh4 = g & 3;
        const int py = pos4 / 3, px = pos4 % 3;
        float svs = 0.f, cvs = 0.f, mass = 0.f;
        #pragma unroll
        for (int i = 0; i < 9; ++i) {
            int s = qq*9 + i;
            unsigned pp = u.svcv[pos4*144 + hh4*36 + s];
            svs += bflo(pp); cvs += bfhi(pp);
            int kk = s >> 2, h2 = s & 3;
            int nbr = (py + kk/3)*5 + (px + kk%3);
            mass += sact[nbr*4 + h2];
        }
        svs += __shfl_xor(svs, 1); cvs += __shfl_xor(cvs, 1); mass += __shfl_xor(mass, 1);
        svs += __shfl_xor(svs, 2); cvs += __shfl_xor(cvs, 2); mass += __shfl_xor(mass, 2);
        if (qq == 0) {
            mass = fmaxf(mass, 1e-6f);
            const float support  = svs / mass;
            const float conflict = cvs / mass;
            const int bph = (b*PPOS + (y0 + py)*SIDE + x0 + px)*NHYP + hh4;
            const float pd = drive[bph]  + support;
            const float pr = resist[bph] + conflict;
            float e = fminf(fmaxf(pd - pr + cst[WS_SC+2], -3.f), 3.f);
            const float a = 1.f / (1.f + expf(-e));
            out[0*NOUT + bph] = support;
            out[1*NOUT + bph] = conflict;
            out[2*NOUT + bph] = pd;
            out[3*NOUT + bph] = pr;
            out[4*NOUT + bph] = e;
            out[5*NOUT + bph] = a;
            out[6*NOUT + bph] = mass;
            bl = a;
            en = -(a*logf(a + 1e-8f) + (1.f - a)*logf(1.f - a + 1e-8f));
            ar = (a > 0.5f) ? 1.f : 0.f;
        }
    }
    if (tid < 128) {   // waves 0,1 fully active: safe shuffles; lanes>=96 carry zeros
        #pragma unroll
        for (int off = 32; off > 0; off >>= 1) {
            bl += __shfl_down(bl, off); en += __shfl_down(en, off); ar += __shfl_down(ar, off);
        }
        if ((tid & 63) == 0) {
            sdot[(tid >> 6)*4 + 0] = bl;
            sdot[(tid >> 6)*4 + 1] = en;
            sdot[(tid >> 6)*4 + 2] = ar;
        }
    }
    __syncthreads();
    if (tid == 0) {
        part[blk]          = sdot[0] + sdot[4];
        part[NBLK + blk]   = sdot[1] + sdot[5];
        part[2*NBLK + blk] = sdot[2] + sdot[6];
    }
}

// ---------------- final: reduce per-block partials ----------------
__global__ __launch_bounds__(256) void eml_final(const float* __restrict__ part, float* __restrict__ out3)
{
    __shared__ float red[4*3];
    float bl = 0.f, en = 0.f, ar = 0.f;
    for (int i = threadIdx.x; i < NBLK; i += 256) {
        bl += part[i];
        en += part[NBLK + i];
        ar += part[2*NBLK + i];
    }
    #pragma unroll
    for (int off = 32; off > 0; off >>= 1) {
        bl += __shfl_down(bl, off); en += __shfl_down(en, off); ar += __shfl_down(ar, off);
    }
    const int lane = threadIdx.x & 63, wid = threadIdx.x >> 6;
    if (lane == 0) { red[wid*3] = bl; red[wid*3+1] = en; red[wid*3+2] = ar; }
    __syncthreads();
    if (threadIdx.x == 0) {
        float b2 = 0.f, e2 = 0.f, a2 = 0.f;
        for (int w = 0; w < 4; ++w) { b2 += red[w*3]; e2 += red[w*3+1]; a2 += red[w*3+2]; }
        const float inv = 1.0f / (float)NOUT;
        out3[0] = b2*inv; out3[1] = e2*inv; out3[2] = a2*inv;
    }
}

extern "C" void kernel_launch(void* const* d_in, const int* in_sizes, int n_in,
                              void* d_out, int out_size, void* d_ws, size_t ws_size,
                              hipStream_t stream)
{
    (void)in_sizes; (void)n_in; (void)out_size; (void)ws_size;
    const float* hs    = (const float*)d_in[0];
    const float* act   = (const float*)d_in[1];
    const float* drv   = (const float*)d_in[2];
    const float* res   = (const float*)d_in[3];
    const float* rel   = (const float*)d_in[4];
    const float* lnw   = (const float*)d_in[5];
    const float* lnb   = (const float*)d_in[6];
    const float* sw1   = (const float*)d_in[7];
    const float* sb1   = (const float*)d_in[8];
    const float* sw2   = (const float*)d_in[9];
    const float* sb2   = (const float*)d_in[10];
    const float* cw1   = (const float*)d_in[11];
    const float* cb1   = (const float*)d_in[12];
    const float* cw2   = (const float*)d_in[13];
    const float* cb2   = (const float*)d_in[14];
    const float* ebias = (const float*)d_in[15];
    float* out = (float*)d_out;
    float* ws  = (float*)d_ws;

    eml_fold<<<dim3(12), dim3(512), 0, stream>>>(
        rel, lnw, lnb, sw1, sb1, sw2, sb2, cw1, cb1, cw2, cb2, ebias, ws);
    eml_main<<<dim3(NBLK), dim3(THREADS), 0, stream>>>(
        hs, act, drv, res, out, ws, ws + WS_PART);
    eml_final<<<dim3(1), dim3(256), 0, stream>>>(ws + WS_PART, out + 7*NOUT);
}